// Round 4
// baseline (591.472 us; speedup 1.0000x reference)
//
#include <hip/hip_runtime.h>
#include <hip/hip_bf16.h>

// GraphSAGE on MI355X — bf16/MFMA + MLP gather + parallel-scan prep (R9).
// R9 changes vs R8 (overhead reduction; NO numeric-path changes):
//  - gs_batch1: one heterogeneous launch (blockIdx.z dispatch) fusing the
//    independent prep: ideg zero + bn-counter zero (z=0), all 9 weight
//    transpose/converts incl. W1T (z=1..9), concat (z=10).
//  - gs_scan_apply absorbs gs_scan_bsum: each block redundantly scans the
//    256 block sums (phase A) then does its per-node scan (phase B).
//  - gs_mlp1_pool_bn: bn+mlp2 fused via last-block pattern (agent-scope
//    atomics for pooled + counter -> cross-XCD coherent).
//  Launches: 19 -> 15.
// R8 (kept): 8-wave 256x256 dbuf GEMM, counted vmcnt(8), both-sides XOR
//    swizzle, setprio around MFMA. R7/R6 (kept): swapped-operand MFMA ->
//    vectorized epilogue; 16 B/lane 2-row agg gathers (pad-8).
//
// Layers: D = [agg | h] @ [Wl ; Wr] as ONE K=512 (K=256 for layer0) bf16 MFMA GEMM.
// Feature buffers: P0/P1 = [N+1,512] bf16 (cols 0..255 agg, 256..511 h), ping-pong.
// Row N is an all-zero pad row; CSR segments are padded to a multiple of 8 edges
// pointing at row N so the gather loop runs 4 independent 2-row loads per iter.

#define NN 65536
#define EE 524288
#define ROWS 65537            // N + zero pad row
#define PCSR_CAP 983040       // E + 7*N upper bound (pad to multiple of 8)

using frag16 = __attribute__((ext_vector_type(8))) short;   // 8 x bf16
using f32x4  = __attribute__((ext_vector_type(4))) float;
using us8    = __attribute__((ext_vector_type(8))) unsigned short;
using us4v   = __attribute__((ext_vector_type(4))) unsigned short;

__device__ __forceinline__ float b2f(unsigned short u) {
    union { unsigned u32; float f; } x; x.u32 = (unsigned)u << 16; return x.f;
}

__device__ __forceinline__ void gld_lds16(const void* g, void* l) {
    __builtin_amdgcn_global_load_lds(
        (const __attribute__((address_space(1))) void*)g,
        (__attribute__((address_space(3))) void*)l, 16, 0, 0);
}

// ---------------- batch-1: independent prep in one launch ----------------
struct B1Args {
    const float* tsrc[9];
    __hip_bfloat16* tdst[9];
    int ldk[9];
    int kofs[9];
    int kblk[9];
    const float *x, *g0, *g1, *g2;
    __hip_bfloat16* h;        // concat dst (P0)
    int* ideg;
    int* bn_cnt;
};

__global__ void gs_batch1(B1Args a) {
    const int z = blockIdx.z;
    const int t = threadIdx.x;
    __shared__ float tile[32][33];
    if (z == 0) {                      // ideg zero + counter zero
        if (blockIdx.y != 0) return;
        int i = blockIdx.x * 256 + t;
        if (i < NN) a.ideg[i] = 0;
        if (blockIdx.x == 0 && t == 0) *a.bn_cnt = 0;
        return;
    }
    if (z <= 9) {                      // weight transpose+convert, mat m = z-1
        const int m = z - 1;
        if ((int)blockIdx.x >= a.kblk[m]) return;
        const float* src = a.tsrc[m];
        __hip_bfloat16* dst = a.tdst[m];
        int ldk = a.ldk[m], kofs = a.kofs[m];
        int kb = blockIdx.x * 32, nb = blockIdx.y * 32;
        int tx = t & 31, ty = t >> 5;
#pragma unroll
        for (int i2 = 0; i2 < 32; i2 += 8)
            tile[ty + i2][tx] = src[(size_t)(kb + ty + i2) * 256 + nb + tx];
        __syncthreads();
#pragma unroll
        for (int i2 = 0; i2 < 32; i2 += 8) {
            int n = nb + ty + i2, k = kb + tx;
            dst[(size_t)n * ldk + kofs + k] = __float2bfloat16(tile[tx][ty + i2]);
        }
        return;
    }
    // z == 10: concat -> bf16 h0 at P0 cols 256..383 (float4 vectorized)
    int vb0 = blockIdx.y * 256 + blockIdx.x;      // 0..2047
#pragma unroll
    for (int s = 0; s < 4; ++s) {
        int idx = (s * 2048 + vb0) * 256 + t;     // covers NN*32 threads' work
        int n = idx >> 5, q = idx & 31;
        int c0 = q * 4;
        const float* src = (c0 < 32) ? (a.x  + (size_t)n * 32 + c0)
                         : (c0 < 64) ? (a.g0 + (size_t)n * 32 + (c0 - 32))
                         : (c0 < 96) ? (a.g1 + (size_t)n * 32 + (c0 - 64))
                                     : (a.g2 + (size_t)n * 32 + (c0 - 96));
        f32x4 v = *(const f32x4*)src;
        union { us4v u; __hip_bfloat16 b[4]; } o;
#pragma unroll
        for (int r = 0; r < 4; ++r) o.b[r] = __float2bfloat16(v[r]);
        *(us4v*)(a.h + (size_t)n * 512 + 256 + c0) = o.u;
    }
}

// ---------------- graph prep ----------------

__global__ void gs_hist(const int* __restrict__ dst, int* __restrict__ deg) {
    int e = blockIdx.x * 256 + threadIdx.x;
    atomicAdd(&deg[dst[e]], 1);
}

// phase 1: per-block (256 nodes) sum of padded degrees -> bsum[256]
__global__ void gs_deg_reduce(const int* __restrict__ deg, int* __restrict__ bsum) {
    int t = threadIdx.x;
    int p = (deg[blockIdx.x * 256 + t] + 7) & ~7;
#pragma unroll
    for (int off = 32; off > 0; off >>= 1) p += __shfl_down(p, off);
    __shared__ int w4[4];
    if ((t & 63) == 0) w4[t >> 6] = p;
    __syncthreads();
    if (t == 0) bsum[blockIdx.x] = w4[0] + w4[1] + w4[2] + w4[3];
}

// phase 2 (fused): every block scans bsum itself, then per-node scan + apply;
// fills pad slots of each segment; zeroes pad rows; sets prow[NN].
__global__ void gs_scan_apply(const int* __restrict__ deg, const int* __restrict__ bsum,
                              int* __restrict__ prow, int* __restrict__ cursor,
                              float* __restrict__ inv_cnt, int* __restrict__ pcsr,
                              __hip_bfloat16* __restrict__ P0,
                              __hip_bfloat16* __restrict__ P1) {
    __shared__ int part[256];
    int t = threadIdx.x;
    // phase A: inclusive scan of the 256 block sums (redundant per block)
    part[t] = bsum[t];
    __syncthreads();
    for (int off = 1; off < 256; off <<= 1) {
        int add = (t >= off) ? part[t - off] : 0;
        __syncthreads();
        part[t] += add;
        __syncthreads();
    }
    int blk_ofs = part[blockIdx.x] - bsum[blockIdx.x];   // exclusive prefix of this block
    int total = part[255];
    __syncthreads();
    // phase B: per-node scan within the block
    int i = blockIdx.x * 256 + t;
    int d = deg[i];
    int p = (d + 7) & ~7;
    part[t] = p;
    __syncthreads();
    for (int off = 1; off < 256; off <<= 1) {
        int add = (t >= off) ? part[t - off] : 0;
        __syncthreads();
        part[t] += add;
        __syncthreads();
    }
    int beg = blk_ofs + part[t] - p;
    prow[i] = beg;
    cursor[i] = beg;
    inv_cnt[i] = 1.0f / (float)(d > 0 ? d : 1);
    for (int j = d; j < p; ++j) pcsr[beg + j] = NN;
    if (i == NN - 1) prow[NN] = total;
    if (blockIdx.x == 0) {
        ((unsigned*)(P0 + (size_t)NN * 512))[t] = 0u;   // 256 x 4B = 1 KB = full pad row
        ((unsigned*)(P1 + (size_t)NN * 512))[t] = 0u;
    }
}

__global__ void gs_bucket(const int* __restrict__ src, const int* __restrict__ dst,
                          int* __restrict__ cursor, int* __restrict__ pcsr) {
    int e = blockIdx.x * 256 + threadIdx.x;
    int d = dst[e];
    int p = atomicAdd(&cursor[d], 1);
    pcsr[p] = src[e];
}

// ---------------- mean aggregation: 8 edges/iter, 2 rows per load instr ----------------
template <int DIM>
__global__ void gs_agg_bf(const __hip_bfloat16* __restrict__ hsrc,
                          __hip_bfloat16* __restrict__ adst,
                          const int* __restrict__ prow, const int* __restrict__ pcsr,
                          const float* __restrict__ inv_cnt) {
    constexpr int EL = DIM / 32;     // elems per lane: 4 (DIM=128) or 8 (DIM=256)
    int wave = threadIdx.x >> 6;
    int lane = threadIdx.x & 63;
    int n = blockIdx.x * 4 + wave;
    int e = prow[n], pe = prow[n + 1];
    float iv = inv_cnt[n];
    const int half = lane >> 5;                      // 0: even edges, 1: odd edges
    const __hip_bfloat16* base = hsrc + (lane & 31) * EL;
    float a[EL];
#pragma unroll
    for (int k = 0; k < EL; ++k) a[k] = 0.f;
    int4 sa, sb;
    if (e < pe) { sa = *(const int4*)(pcsr + e); sb = *(const int4*)(pcsr + e + 4); }
    while (e < pe) {
        int4 ca = sa, cb = sb;
        e += 8;
        if (e < pe) { sa = *(const int4*)(pcsr + e); sb = *(const int4*)(pcsr + e + 4); }
        int r0 = half ? ca.y : ca.x;
        int r1 = half ? ca.w : ca.z;
        int r2 = half ? cb.y : cb.x;
        int r3 = half ? cb.w : cb.z;
        if constexpr (DIM == 256) {
            us8 v0 = *(const us8*)(base + (size_t)r0 * 512);
            us8 v1 = *(const us8*)(base + (size_t)r1 * 512);
            us8 v2 = *(const us8*)(base + (size_t)r2 * 512);
            us8 v3 = *(const us8*)(base + (size_t)r3 * 512);
#pragma unroll
            for (int k = 0; k < 8; ++k)
                a[k] += b2f(v0[k]) + b2f(v1[k]) + b2f(v2[k]) + b2f(v3[k]);
        } else {
            us4v v0 = *(const us4v*)(base + (size_t)r0 * 512);
            us4v v1 = *(const us4v*)(base + (size_t)r1 * 512);
            us4v v2 = *(const us4v*)(base + (size_t)r2 * 512);
            us4v v3 = *(const us4v*)(base + (size_t)r3 * 512);
#pragma unroll
            for (int k = 0; k < 4; ++k)
                a[k] += b2f(v0[k]) + b2f(v1[k]) + b2f(v2[k]) + b2f(v3[k]);
        }
    }
#pragma unroll
    for (int k = 0; k < EL; ++k) a[k] += __shfl_xor(a[k], 32);
    if (half == 0) {
        union { us8 v8; us4v v4; __hip_bfloat16 b[8]; } o;
#pragma unroll
        for (int k = 0; k < EL; ++k) o.b[k] = __float2bfloat16(a[k] * iv);
        if constexpr (DIM == 256)
            *(us8*)(adst + (size_t)n * 512 + (lane & 31) * 8) = o.v8;
        else
            *(us4v*)(adst + (size_t)n * 512 + (lane & 31) * 4) = o.v4;
    }
}

// ---------------- MFMA GEMM core: 256x256 tile, 8 waves, BK=64, dbuf + counted vmcnt ----
// (unchanged from R8 — passed verification there)

__device__ __forceinline__ void stage_tile256(const __hip_bfloat16* __restrict__ A, int lda,
                                              const __hip_bfloat16* __restrict__ Bt, int ldb,
                                              size_t row0, int kc,
                                              __hip_bfloat16* As, __hip_bfloat16* Bs) {
    const int t = threadIdx.x;    // 512
#pragma unroll
    for (int l = 0; l < 4; ++l) {
        int c = l * 512 + t;                  // 2048 16B-chunks per matrix
        int row = c >> 3;                     // 0..255
        int col = ((c & 7) ^ (row & 7)) * 8;  // pre-swizzled source column
        gld_lds16(A + (row0 + row) * (size_t)lda + kc + col, As + c * 8);
        gld_lds16(Bt + (size_t)row * ldb + kc + col, Bs + c * 8);
    }
}

__device__ __forceinline__ void compute_tile256(const __hip_bfloat16* As,
                                                const __hip_bfloat16* Bs,
                                                int wm, int wn, int ml, int cq,
                                                f32x4 (&acc)[8][4]) {
#pragma unroll
    for (int kk = 0; kk < 2; ++kk) {          // two K=32 halves of the 64-wide tile
        const int g = kk * 4 + cq;            // logical 16B chunk 0..7
        frag16 a[8], b[4];
#pragma unroll
        for (int i = 0; i < 8; ++i) {
            int row = wm * 128 + i * 16 + ml;
            a[i] = *(const frag16*)(As + row * 64 + ((g ^ (row & 7)) * 8));
        }
#pragma unroll
        for (int j = 0; j < 4; ++j) {
            int row = wn * 64 + j * 16 + ml;
            b[j] = *(const frag16*)(Bs + row * 64 + ((g ^ (row & 7)) * 8));
        }
        __builtin_amdgcn_s_setprio(1);
#pragma unroll
        for (int i = 0; i < 8; ++i)
#pragma unroll
            for (int j = 0; j < 4; ++j)
                acc[i][j] = __builtin_amdgcn_mfma_f32_16x16x32_bf16(b[j], a[i], acc[i][j], 0, 0, 0);
        __builtin_amdgcn_s_setprio(0);
    }
}

__device__ __forceinline__ void gemm256_loop(const __hip_bfloat16* __restrict__ A, int lda,
                                             const __hip_bfloat16* __restrict__ Bt, int ldb,
                                             size_t row0, int kbeg, int nt,
                                             __hip_bfloat16 (&As)[2][256 * 64],
                                             __hip_bfloat16 (&Bs)[2][256 * 64],
                                             int wm, int wn, int ml, int cq,
                                             f32x4 (&acc)[8][4]) {
    stage_tile256(A, lda, Bt, ldb, row0, kbeg, As[0], Bs[0]);
    int cur = 0;
    for (int kt = 0; kt < nt; ++kt) {
        if (kt + 1 < nt) {
            stage_tile256(A, lda, Bt, ldb, row0, kbeg + (kt + 1) * 64, As[cur ^ 1], Bs[cur ^ 1]);
            asm volatile("s_waitcnt vmcnt(8)" ::: "memory");   // cur's 8 loads done; next's stay in flight
        } else {
            asm volatile("s_waitcnt vmcnt(0)" ::: "memory");
        }
        asm volatile("s_barrier" ::: "memory");                // tile resident for all waves
        compute_tile256(As[cur], Bs[cur], wm, wn, ml, cq, acc);
        asm volatile("s_barrier" ::: "memory");                // all waves done reading buf[cur]
        cur ^= 1;
    }
}

__global__ __launch_bounds__(512, 2)
void gs_gemm8_bias_relu(const __hip_bfloat16* __restrict__ A, int lda, int K,
                        const __hip_bfloat16* __restrict__ Bt, int ldb,
                        const float* __restrict__ bias,
                        __hip_bfloat16* __restrict__ C, int ldc, int cofs) {
    __shared__ __hip_bfloat16 As[2][256 * 64];
    __shared__ __hip_bfloat16 Bs[2][256 * 64];
    f32x4 acc[8][4] = {};
    const size_t row0 = (size_t)blockIdx.x * 256;
    const int lane = threadIdx.x & 63, wid = threadIdx.x >> 6;
    const int wm = wid >> 2, wn = wid & 3, ml = lane & 15, cq = lane >> 4;
    gemm256_loop(A, lda, Bt, ldb, row0, 0, K / 64, As, Bs, wm, wn, ml, cq, acc);
#pragma unroll
    for (int i = 0; i < 8; ++i) {
        size_t row = row0 + wm * 128 + i * 16 + ml;
#pragma unroll
        for (int j = 0; j < 4; ++j) {
            int n0 = wn * 64 + j * 16 + cq * 4;
            f32x4 bv = *(const f32x4*)(bias + n0);
            union { us4v v; __hip_bfloat16 b[4]; } o;
#pragma unroll
            for (int r = 0; r < 4; ++r)
                o.b[r] = __float2bfloat16(fmaxf(acc[i][j][r] + bv[r], 0.f));
            *(us4v*)(C + row * (size_t)ldc + cofs + n0) = o.v;
        }
    }
}

__global__ __launch_bounds__(512, 2)
void gs_gemm8_splitk(const __hip_bfloat16* __restrict__ A, int lda,
                     const __hip_bfloat16* __restrict__ Bt, int ldb,
                     float* __restrict__ part) {
    __shared__ __hip_bfloat16 As[2][256 * 64];
    __shared__ __hip_bfloat16 Bs[2][256 * 64];
    f32x4 acc[8][4] = {};
    const size_t row0 = (size_t)blockIdx.x * 256;
    const int kbeg = blockIdx.y * 512;                  // z-slice of K=8192
    const int lane = threadIdx.x & 63, wid = threadIdx.x >> 6;
    const int wm = wid >> 2, wn = wid & 3, ml = lane & 15, cq = lane >> 4;
    gemm256_loop(A, lda, Bt, ldb, row0, kbeg, 8, As, Bs, wm, wn, ml, cq, acc);
    float* p = part + (size_t)blockIdx.y * 2048 * 256;
#pragma unroll
    for (int i = 0; i < 8; ++i) {
        size_t row = row0 + wm * 128 + i * 16 + ml;
#pragma unroll
        for (int j = 0; j < 4; ++j) {
            int n0 = wn * 64 + j * 16 + cq * 4;
            *(f32x4*)(p + row * 256 + n0) = acc[i][j];
        }
    }
}

// fused: t1 = relu(sum_k part + b1); pooled = t1.W2 + b2; last block does BN+MLP2.
__global__ void gs_mlp1_pool_bn(const float* __restrict__ part, const float* __restrict__ b1,
                                const float* __restrict__ W2, const float* __restrict__ b2,
                                float* __restrict__ pooled, int* __restrict__ cnt,
                                const float* __restrict__ gamma, const float* __restrict__ beta,
                                const float* __restrict__ mW1, const float* __restrict__ mb1,
                                const float* __restrict__ mW2, const float* __restrict__ mb2,
                                float* __restrict__ out) {
    __shared__ float w4[4];
    __shared__ int last;
    int r = blockIdx.x;     // 2048
    int t = threadIdx.x;    // 256
    float s = 0.f;
#pragma unroll
    for (int ks = 0; ks < 16; ++ks) s += part[(size_t)ks * 524288 + r * 256 + t];
    s = fmaxf(s + b1[t], 0.f) * W2[t];
#pragma unroll
    for (int off = 32; off > 0; off >>= 1) s += __shfl_down(s, off);
    if ((t & 63) == 0) w4[t >> 6] = s;
    __syncthreads();
    if (t == 0) {
        float pv = w4[0] + w4[1] + w4[2] + w4[3] + b2[0];
        __hip_atomic_store(&pooled[r], pv, __ATOMIC_RELEASE, __HIP_MEMORY_SCOPE_AGENT);
        int old = __hip_atomic_fetch_add(cnt, 1, __ATOMIC_ACQ_REL, __HIP_MEMORY_SCOPE_AGENT);
        last = (old == 2047) ? 1 : 0;
    }
    __syncthreads();
    if (!last) return;
    // ---- final block only: BN + MLP2 -> out[8,8] ----
    __shared__ float hb[8][256];
    __shared__ float h2[8][256];
    {
        float v[8];
        float m = 0.f;
#pragma unroll
        for (int b = 0; b < 8; ++b) {
            v[b] = __hip_atomic_load(&pooled[b * 256 + t], __ATOMIC_RELAXED,
                                     __HIP_MEMORY_SCOPE_AGENT);
            m += v[b];
        }
        m *= 0.125f;
        float var = 0.f;
#pragma unroll
        for (int b = 0; b < 8; ++b) { float d = v[b] - m; var += d * d; }
        var *= 0.125f;
        float is = 1.0f / sqrtf(var + 1e-5f);
        float g = gamma[t], bt = beta[t];
#pragma unroll
        for (int b = 0; b < 8; ++b) hb[b][t] = fmaxf((v[b] - m) * is * g + bt, 0.f);
    }
    __syncthreads();
    {
        float acc[8] = {};
        for (int i = 0; i < 256; ++i) {
            float w = mW1[i * 256 + t];
#pragma unroll
            for (int b = 0; b < 8; ++b) acc[b] = fmaf(hb[b][i], w, acc[b]);
        }
        float bb = mb1[t];
#pragma unroll
        for (int b = 0; b < 8; ++b) h2[b][t] = fmaxf(acc[b] + bb, 0.f);
    }
    __syncthreads();
    if (t < 64) {
        int b = t >> 3, o = t & 7;
        float acc = 0.f;
        for (int j = 0; j < 256; ++j) acc = fmaf(h2[b][j], mW2[j * 8 + o], acc);
        out[b * 8 + o] = acc + mb2[o];
    }
}

extern "C" void kernel_launch(void* const* d_in, const int* in_sizes, int n_in,
                              void* d_out, int out_size, void* d_ws, size_t ws_size,
                              hipStream_t stream) {
    const float* x  = (const float*)d_in[0];
    const float* g0 = (const float*)d_in[1];
    const float* g1 = (const float*)d_in[2];
    const float* g2 = (const float*)d_in[3];
    const int* edge_src = (const int*)d_in[4];
    const int* edge_dst = (const int*)d_in[5];
    const float* Wl[4] = {(const float*)d_in[6], (const float*)d_in[9],
                          (const float*)d_in[12], (const float*)d_in[15]};
    const float* Wr[4] = {(const float*)d_in[7], (const float*)d_in[10],
                          (const float*)d_in[13], (const float*)d_in[16]};
    const float* bs[4] = {(const float*)d_in[8], (const float*)d_in[11],
                          (const float*)d_in[14], (const float*)d_in[17]};
    const float* mlp1_W1 = (const float*)d_in[18];
    const float* mlp1_b1 = (const float*)d_in[19];
    const float* mlp1_W2 = (const float*)d_in[20];
    const float* mlp1_b2 = (const float*)d_in[21];
    const float* bn_gamma = (const float*)d_in[22];
    const float* bn_beta  = (const float*)d_in[23];
    const float* mlp2_W1 = (const float*)d_in[24];
    const float* mlp2_b1 = (const float*)d_in[25];
    const float* mlp2_W2 = (const float*)d_in[26];
    const float* mlp2_b2 = (const float*)d_in[27];
    float* out = (float*)d_out;

    char* ws = (char*)d_ws;
    __hip_bfloat16* P0 = (__hip_bfloat16*)ws;                  // [ROWS][512]
    __hip_bfloat16* P1 = P0 + (size_t)ROWS * 512;              // [ROWS][512]
    __hip_bfloat16* WC0 = P1 + (size_t)ROWS * 512;             // [256][256]
    __hip_bfloat16* WC1 = WC0 + 65536;                         // [256][512]
    __hip_bfloat16* WC2 = WC1 + 131072;
    __hip_bfloat16* WC3 = WC2 + 131072;
    __hip_bfloat16* W1T = WC3 + 131072;                        // [256][8192]
    float* inv_cnt = (float*)(W1T + 2097152);
    int* ideg = (int*)(inv_cnt + 65536);
    int* prow = ideg + 65536;                                  // 65537 (+pad)
    int* cursor = prow + 65544;
    int* bsum = cursor + 65536;                                // 256
    int* bn_cnt = bsum + 256;                                  // 16 (1 used)
    int* pcsr = bn_cnt + 16;                                   // PCSR_CAP
    // overlays (all inside P0/P1, mutually disjoint):
    __hip_bfloat16* H4 = P0;                                   // [2048][8192] bf16 = 32 MB
    float* pooled = (float*)P1 + 524288;                       // 8 KB at P1+2MB
    float* PART = (float*)((char*)P1 + (size_t)(4 << 20));     // 32 MB at P1+4MB

    // --- batch-1: ideg/counter zero + 9 weight tcvt + concat (independent work) ---
    {
        B1Args a;
        const float* srcs[9] = {Wl[0], Wr[0], Wl[1], Wr[1], Wl[2], Wr[2], Wl[3], Wr[3],
                                mlp1_W1};
        __hip_bfloat16* dsts[9] = {WC0, WC0, WC1, WC1, WC2, WC2, WC3, WC3, W1T};
        int ldks[9] = {256, 256, 512, 512, 512, 512, 512, 512, 8192};
        int kofss[9] = {0, 128, 0, 256, 0, 256, 0, 256, 0};
        int kblks[9] = {4, 4, 8, 8, 8, 8, 8, 8, 256};
        for (int i = 0; i < 9; ++i) {
            a.tsrc[i] = srcs[i]; a.tdst[i] = dsts[i];
            a.ldk[i] = ldks[i]; a.kofs[i] = kofss[i]; a.kblk[i] = kblks[i];
        }
        a.x = x; a.g0 = g0; a.g1 = g1; a.g2 = g2;
        a.h = P0; a.ideg = ideg; a.bn_cnt = bn_cnt;
        gs_batch1<<<dim3(256, 8, 11), 256, 0, stream>>>(a);
    }

    // --- graph prep (hist -> reduce -> fused scan+apply -> bucket) ---
    gs_hist<<<EE / 256, 256, 0, stream>>>(edge_dst, ideg);
    gs_deg_reduce<<<256, 256, 0, stream>>>(ideg, bsum);
    gs_scan_apply<<<256, 256, 0, stream>>>(ideg, bsum, prow, cursor, inv_cnt, pcsr, P0, P1);
    gs_bucket<<<EE / 256, 256, 0, stream>>>(edge_src, edge_dst, cursor, pcsr);

    // --- 4 SAGE layers (256x256 deep-pipelined GEMM, 256 blocks = 1/CU) ---
    gs_agg_bf<128><<<NN / 4, 256, 0, stream>>>(P0 + 256, P0 + 128, prow, pcsr, inv_cnt);
    gs_gemm8_bias_relu<<<NN / 256, 512, 0, stream>>>(P0 + 128, 512, 256, WC0, 256,
                                                     bs[0], P1, 512, 256);
    gs_agg_bf<256><<<NN / 4, 256, 0, stream>>>(P1 + 256, P1, prow, pcsr, inv_cnt);
    gs_gemm8_bias_relu<<<NN / 256, 512, 0, stream>>>(P1, 512, 512, WC1, 512,
                                                     bs[1], P0, 512, 256);
    gs_agg_bf<256><<<NN / 4, 256, 0, stream>>>(P0 + 256, P0, prow, pcsr, inv_cnt);
    gs_gemm8_bias_relu<<<NN / 256, 512, 0, stream>>>(P0, 512, 512, WC2, 512,
                                                     bs[2], P1, 512, 256);
    gs_agg_bf<256><<<NN / 4, 256, 0, stream>>>(P1 + 256, P1, prow, pcsr, inv_cnt);
    gs_gemm8_bias_relu<<<NN / 256, 512, 0, stream>>>(P1, 512, 512, WC3, 512,
                                                     bs[3], H4, 256, 0);

    // --- MLP1: [2048,8192] @ [8192,256] bf16 split-K=16 -> fp32 partials ---
    gs_gemm8_splitk<<<dim3(2048 / 256, 16), 512, 0, stream>>>(H4, 8192, W1T, 8192, PART);

    // --- reduce + pool + (last block) BN + MLP2 -> out[8,8] ---
    gs_mlp1_pool_bn<<<2048, 256, 0, stream>>>(PART, mlp1_b1, mlp1_W2, mlp1_b2,
                                              pooled, bn_cnt, bn_gamma, bn_beta,
                                              mlp2_W1, mlp2_b1, mlp2_W2, mlp2_b2, out);
}

// Round 5
// 520.075 us; speedup vs baseline: 1.1373x; 1.1373x over previous
//
#include <hip/hip_runtime.h>
#include <hip/hip_bf16.h>

// GraphSAGE on MI355X — bf16/MFMA + MLP gather + parallel-scan prep (R10).
// R10 changes vs R9:
//  - UN-FUSE bn from mlp1_pool. R9's last-block pattern used agent-scope
//    RELEASE/ACQ_REL atomics; on gfx950 agent-scope release = per-block L2
//    writeback across non-coherent XCD L2s -> gs_mlp1_pool_bn stalled at
//    120 us/dispatch (VALUBusy 0.9%, HBM 1.8%). Plain stores + separate
//    1-block gs_bn_mlp2 kernel restores coherence via the launch boundary.
// R9 (kept): gs_batch1 heterogeneous prep launch; scan_bsum folded into
//    scan_apply. R8 (kept): 8-wave 256x256 dbuf GEMM, counted vmcnt(8),
//    both-sides XOR swizzle, setprio. R7/R6 (kept): swapped-operand MFMA
//    epilogue; 16 B/lane 2-row agg gathers (pad-8).
//
// Layers: D = [agg | h] @ [Wl ; Wr] as ONE K=512 (K=256 for layer0) bf16 MFMA GEMM.
// Feature buffers: P0/P1 = [N+1,512] bf16 (cols 0..255 agg, 256..511 h), ping-pong.
// Row N is an all-zero pad row; CSR segments are padded to a multiple of 8 edges
// pointing at row N so the gather loop runs 4 independent 2-row loads per iter.

#define NN 65536
#define EE 524288
#define ROWS 65537            // N + zero pad row
#define PCSR_CAP 983040       // E + 7*N upper bound (pad to multiple of 8)

using frag16 = __attribute__((ext_vector_type(8))) short;   // 8 x bf16
using f32x4  = __attribute__((ext_vector_type(4))) float;
using us8    = __attribute__((ext_vector_type(8))) unsigned short;
using us4v   = __attribute__((ext_vector_type(4))) unsigned short;

__device__ __forceinline__ float b2f(unsigned short u) {
    union { unsigned u32; float f; } x; x.u32 = (unsigned)u << 16; return x.f;
}

__device__ __forceinline__ void gld_lds16(const void* g, void* l) {
    __builtin_amdgcn_global_load_lds(
        (const __attribute__((address_space(1))) void*)g,
        (__attribute__((address_space(3))) void*)l, 16, 0, 0);
}

// ---------------- batch-1: independent prep in one launch ----------------
struct B1Args {
    const float* tsrc[9];
    __hip_bfloat16* tdst[9];
    int ldk[9];
    int kofs[9];
    int kblk[9];
    const float *x, *g0, *g1, *g2;
    __hip_bfloat16* h;        // concat dst (P0)
    int* ideg;
};

__global__ void gs_batch1(B1Args a) {
    const int z = blockIdx.z;
    const int t = threadIdx.x;
    __shared__ float tile[32][33];
    if (z == 0) {                      // ideg zero
        if (blockIdx.y != 0) return;
        int i = blockIdx.x * 256 + t;
        if (i < NN) a.ideg[i] = 0;
        return;
    }
    if (z <= 9) {                      // weight transpose+convert, mat m = z-1
        const int m = z - 1;
        if ((int)blockIdx.x >= a.kblk[m]) return;
        const float* src = a.tsrc[m];
        __hip_bfloat16* dst = a.tdst[m];
        int ldk = a.ldk[m], kofs = a.kofs[m];
        int kb = blockIdx.x * 32, nb = blockIdx.y * 32;
        int tx = t & 31, ty = t >> 5;
#pragma unroll
        for (int i2 = 0; i2 < 32; i2 += 8)
            tile[ty + i2][tx] = src[(size_t)(kb + ty + i2) * 256 + nb + tx];
        __syncthreads();
#pragma unroll
        for (int i2 = 0; i2 < 32; i2 += 8) {
            int n = nb + ty + i2, k = kb + tx;
            dst[(size_t)n * ldk + kofs + k] = __float2bfloat16(tile[tx][ty + i2]);
        }
        return;
    }
    // z == 10: concat -> bf16 h0 at P0 cols 256..383 (float4 vectorized)
    int vb0 = blockIdx.y * 256 + blockIdx.x;      // 0..2047
#pragma unroll
    for (int s = 0; s < 4; ++s) {
        int idx = (s * 2048 + vb0) * 256 + t;     // covers NN*32 threads' work
        int n = idx >> 5, q = idx & 31;
        int c0 = q * 4;
        const float* src = (c0 < 32) ? (a.x  + (size_t)n * 32 + c0)
                         : (c0 < 64) ? (a.g0 + (size_t)n * 32 + (c0 - 32))
                         : (c0 < 96) ? (a.g1 + (size_t)n * 32 + (c0 - 64))
                                     : (a.g2 + (size_t)n * 32 + (c0 - 96));
        f32x4 v = *(const f32x4*)src;
        union { us4v u; __hip_bfloat16 b[4]; } o;
#pragma unroll
        for (int r = 0; r < 4; ++r) o.b[r] = __float2bfloat16(v[r]);
        *(us4v*)(a.h + (size_t)n * 512 + 256 + c0) = o.u;
    }
}

// ---------------- graph prep ----------------

__global__ void gs_hist(const int* __restrict__ dst, int* __restrict__ deg) {
    int e = blockIdx.x * 256 + threadIdx.x;
    atomicAdd(&deg[dst[e]], 1);
}

// phase 1: per-block (256 nodes) sum of padded degrees -> bsum[256]
__global__ void gs_deg_reduce(const int* __restrict__ deg, int* __restrict__ bsum) {
    int t = threadIdx.x;
    int p = (deg[blockIdx.x * 256 + t] + 7) & ~7;
#pragma unroll
    for (int off = 32; off > 0; off >>= 1) p += __shfl_down(p, off);
    __shared__ int w4[4];
    if ((t & 63) == 0) w4[t >> 6] = p;
    __syncthreads();
    if (t == 0) bsum[blockIdx.x] = w4[0] + w4[1] + w4[2] + w4[3];
}

// phase 2 (fused): every block scans bsum itself, then per-node scan + apply;
// fills pad slots of each segment; zeroes pad rows; sets prow[NN].
__global__ void gs_scan_apply(const int* __restrict__ deg, const int* __restrict__ bsum,
                              int* __restrict__ prow, int* __restrict__ cursor,
                              float* __restrict__ inv_cnt, int* __restrict__ pcsr,
                              __hip_bfloat16* __restrict__ P0,
                              __hip_bfloat16* __restrict__ P1) {
    __shared__ int part[256];
    int t = threadIdx.x;
    // phase A: inclusive scan of the 256 block sums (redundant per block)
    part[t] = bsum[t];
    __syncthreads();
    for (int off = 1; off < 256; off <<= 1) {
        int add = (t >= off) ? part[t - off] : 0;
        __syncthreads();
        part[t] += add;
        __syncthreads();
    }
    int blk_ofs = part[blockIdx.x] - bsum[blockIdx.x];   // exclusive prefix of this block
    int total = part[255];
    __syncthreads();
    // phase B: per-node scan within the block
    int i = blockIdx.x * 256 + t;
    int d = deg[i];
    int p = (d + 7) & ~7;
    part[t] = p;
    __syncthreads();
    for (int off = 1; off < 256; off <<= 1) {
        int add = (t >= off) ? part[t - off] : 0;
        __syncthreads();
        part[t] += add;
        __syncthreads();
    }
    int beg = blk_ofs + part[t] - p;
    prow[i] = beg;
    cursor[i] = beg;
    inv_cnt[i] = 1.0f / (float)(d > 0 ? d : 1);
    for (int j = d; j < p; ++j) pcsr[beg + j] = NN;
    if (i == NN - 1) prow[NN] = total;
    if (blockIdx.x == 0) {
        ((unsigned*)(P0 + (size_t)NN * 512))[t] = 0u;   // 256 x 4B = 1 KB = full pad row
        ((unsigned*)(P1 + (size_t)NN * 512))[t] = 0u;
    }
}

__global__ void gs_bucket(const int* __restrict__ src, const int* __restrict__ dst,
                          int* __restrict__ cursor, int* __restrict__ pcsr) {
    int e = blockIdx.x * 256 + threadIdx.x;
    int d = dst[e];
    int p = atomicAdd(&cursor[d], 1);
    pcsr[p] = src[e];
}

// ---------------- mean aggregation: 8 edges/iter, 2 rows per load instr ----------------
template <int DIM>
__global__ void gs_agg_bf(const __hip_bfloat16* __restrict__ hsrc,
                          __hip_bfloat16* __restrict__ adst,
                          const int* __restrict__ prow, const int* __restrict__ pcsr,
                          const float* __restrict__ inv_cnt) {
    constexpr int EL = DIM / 32;     // elems per lane: 4 (DIM=128) or 8 (DIM=256)
    int wave = threadIdx.x >> 6;
    int lane = threadIdx.x & 63;
    int n = blockIdx.x * 4 + wave;
    int e = prow[n], pe = prow[n + 1];
    float iv = inv_cnt[n];
    const int half = lane >> 5;                      // 0: even edges, 1: odd edges
    const __hip_bfloat16* base = hsrc + (lane & 31) * EL;
    float a[EL];
#pragma unroll
    for (int k = 0; k < EL; ++k) a[k] = 0.f;
    int4 sa, sb;
    if (e < pe) { sa = *(const int4*)(pcsr + e); sb = *(const int4*)(pcsr + e + 4); }
    while (e < pe) {
        int4 ca = sa, cb = sb;
        e += 8;
        if (e < pe) { sa = *(const int4*)(pcsr + e); sb = *(const int4*)(pcsr + e + 4); }
        int r0 = half ? ca.y : ca.x;
        int r1 = half ? ca.w : ca.z;
        int r2 = half ? cb.y : cb.x;
        int r3 = half ? cb.w : cb.z;
        if constexpr (DIM == 256) {
            us8 v0 = *(const us8*)(base + (size_t)r0 * 512);
            us8 v1 = *(const us8*)(base + (size_t)r1 * 512);
            us8 v2 = *(const us8*)(base + (size_t)r2 * 512);
            us8 v3 = *(const us8*)(base + (size_t)r3 * 512);
#pragma unroll
            for (int k = 0; k < 8; ++k)
                a[k] += b2f(v0[k]) + b2f(v1[k]) + b2f(v2[k]) + b2f(v3[k]);
        } else {
            us4v v0 = *(const us4v*)(base + (size_t)r0 * 512);
            us4v v1 = *(const us4v*)(base + (size_t)r1 * 512);
            us4v v2 = *(const us4v*)(base + (size_t)r2 * 512);
            us4v v3 = *(const us4v*)(base + (size_t)r3 * 512);
#pragma unroll
            for (int k = 0; k < 4; ++k)
                a[k] += b2f(v0[k]) + b2f(v1[k]) + b2f(v2[k]) + b2f(v3[k]);
        }
    }
#pragma unroll
    for (int k = 0; k < EL; ++k) a[k] += __shfl_xor(a[k], 32);
    if (half == 0) {
        union { us8 v8; us4v v4; __hip_bfloat16 b[8]; } o;
#pragma unroll
        for (int k = 0; k < EL; ++k) o.b[k] = __float2bfloat16(a[k] * iv);
        if constexpr (DIM == 256)
            *(us8*)(adst + (size_t)n * 512 + (lane & 31) * 8) = o.v8;
        else
            *(us4v*)(adst + (size_t)n * 512 + (lane & 31) * 4) = o.v4;
    }
}

// ---------------- MFMA GEMM core: 256x256 tile, 8 waves, BK=64, dbuf + counted vmcnt ----
// (unchanged from R8 — passed verification there)

__device__ __forceinline__ void stage_tile256(const __hip_bfloat16* __restrict__ A, int lda,
                                              const __hip_bfloat16* __restrict__ Bt, int ldb,
                                              size_t row0, int kc,
                                              __hip_bfloat16* As, __hip_bfloat16* Bs) {
    const int t = threadIdx.x;    // 512
#pragma unroll
    for (int l = 0; l < 4; ++l) {
        int c = l * 512 + t;                  // 2048 16B-chunks per matrix
        int row = c >> 3;                     // 0..255
        int col = ((c & 7) ^ (row & 7)) * 8;  // pre-swizzled source column
        gld_lds16(A + (row0 + row) * (size_t)lda + kc + col, As + c * 8);
        gld_lds16(Bt + (size_t)row * ldb + kc + col, Bs + c * 8);
    }
}

__device__ __forceinline__ void compute_tile256(const __hip_bfloat16* As,
                                                const __hip_bfloat16* Bs,
                                                int wm, int wn, int ml, int cq,
                                                f32x4 (&acc)[8][4]) {
#pragma unroll
    for (int kk = 0; kk < 2; ++kk) {          // two K=32 halves of the 64-wide tile
        const int g = kk * 4 + cq;            // logical 16B chunk 0..7
        frag16 a[8], b[4];
#pragma unroll
        for (int i = 0; i < 8; ++i) {
            int row = wm * 128 + i * 16 + ml;
            a[i] = *(const frag16*)(As + row * 64 + ((g ^ (row & 7)) * 8));
        }
#pragma unroll
        for (int j = 0; j < 4; ++j) {
            int row = wn * 64 + j * 16 + ml;
            b[j] = *(const frag16*)(Bs + row * 64 + ((g ^ (row & 7)) * 8));
        }
        __builtin_amdgcn_s_setprio(1);
#pragma unroll
        for (int i = 0; i < 8; ++i)
#pragma unroll
            for (int j = 0; j < 4; ++j)
                acc[i][j] = __builtin_amdgcn_mfma_f32_16x16x32_bf16(b[j], a[i], acc[i][j], 0, 0, 0);
        __builtin_amdgcn_s_setprio(0);
    }
}

__device__ __forceinline__ void gemm256_loop(const __hip_bfloat16* __restrict__ A, int lda,
                                             const __hip_bfloat16* __restrict__ Bt, int ldb,
                                             size_t row0, int kbeg, int nt,
                                             __hip_bfloat16 (&As)[2][256 * 64],
                                             __hip_bfloat16 (&Bs)[2][256 * 64],
                                             int wm, int wn, int ml, int cq,
                                             f32x4 (&acc)[8][4]) {
    stage_tile256(A, lda, Bt, ldb, row0, kbeg, As[0], Bs[0]);
    int cur = 0;
    for (int kt = 0; kt < nt; ++kt) {
        if (kt + 1 < nt) {
            stage_tile256(A, lda, Bt, ldb, row0, kbeg + (kt + 1) * 64, As[cur ^ 1], Bs[cur ^ 1]);
            asm volatile("s_waitcnt vmcnt(8)" ::: "memory");   // cur's 8 loads done; next's stay in flight
        } else {
            asm volatile("s_waitcnt vmcnt(0)" ::: "memory");
        }
        asm volatile("s_barrier" ::: "memory");                // tile resident for all waves
        compute_tile256(As[cur], Bs[cur], wm, wn, ml, cq, acc);
        asm volatile("s_barrier" ::: "memory");                // all waves done reading buf[cur]
        cur ^= 1;
    }
}

__global__ __launch_bounds__(512, 2)
void gs_gemm8_bias_relu(const __hip_bfloat16* __restrict__ A, int lda, int K,
                        const __hip_bfloat16* __restrict__ Bt, int ldb,
                        const float* __restrict__ bias,
                        __hip_bfloat16* __restrict__ C, int ldc, int cofs) {
    __shared__ __hip_bfloat16 As[2][256 * 64];
    __shared__ __hip_bfloat16 Bs[2][256 * 64];
    f32x4 acc[8][4] = {};
    const size_t row0 = (size_t)blockIdx.x * 256;
    const int lane = threadIdx.x & 63, wid = threadIdx.x >> 6;
    const int wm = wid >> 2, wn = wid & 3, ml = lane & 15, cq = lane >> 4;
    gemm256_loop(A, lda, Bt, ldb, row0, 0, K / 64, As, Bs, wm, wn, ml, cq, acc);
#pragma unroll
    for (int i = 0; i < 8; ++i) {
        size_t row = row0 + wm * 128 + i * 16 + ml;
#pragma unroll
        for (int j = 0; j < 4; ++j) {
            int n0 = wn * 64 + j * 16 + cq * 4;
            f32x4 bv = *(const f32x4*)(bias + n0);
            union { us4v v; __hip_bfloat16 b[4]; } o;
#pragma unroll
            for (int r = 0; r < 4; ++r)
                o.b[r] = __float2bfloat16(fmaxf(acc[i][j][r] + bv[r], 0.f));
            *(us4v*)(C + row * (size_t)ldc + cofs + n0) = o.v;
        }
    }
}

__global__ __launch_bounds__(512, 2)
void gs_gemm8_splitk(const __hip_bfloat16* __restrict__ A, int lda,
                     const __hip_bfloat16* __restrict__ Bt, int ldb,
                     float* __restrict__ part) {
    __shared__ __hip_bfloat16 As[2][256 * 64];
    __shared__ __hip_bfloat16 Bs[2][256 * 64];
    f32x4 acc[8][4] = {};
    const size_t row0 = (size_t)blockIdx.x * 256;
    const int kbeg = blockIdx.y * 512;                  // z-slice of K=8192
    const int lane = threadIdx.x & 63, wid = threadIdx.x >> 6;
    const int wm = wid >> 2, wn = wid & 3, ml = lane & 15, cq = lane >> 4;
    gemm256_loop(A, lda, Bt, ldb, row0, kbeg, 8, As, Bs, wm, wn, ml, cq, acc);
    float* p = part + (size_t)blockIdx.y * 2048 * 256;
#pragma unroll
    for (int i = 0; i < 8; ++i) {
        size_t row = row0 + wm * 128 + i * 16 + ml;
#pragma unroll
        for (int j = 0; j < 4; ++j) {
            int n0 = wn * 64 + j * 16 + cq * 4;
            *(f32x4*)(p + row * 256 + n0) = acc[i][j];
        }
    }
}

// fused: t1 = relu(sum_k part + b1); pooled = t1 . W2 + b2   (one block per row)
// Plain stores only — cross-XCD visibility comes from the kernel-launch boundary.
__global__ void gs_mlp1_pool(const float* __restrict__ part, const float* __restrict__ b1,
                             const float* __restrict__ W2, const float* __restrict__ b2,
                             float* __restrict__ pooled) {
    int r = blockIdx.x;     // 2048
    int t = threadIdx.x;    // 256
    float s = 0.f;
#pragma unroll
    for (int ks = 0; ks < 16; ++ks) s += part[(size_t)ks * 524288 + r * 256 + t];
    s = fmaxf(s + b1[t], 0.f) * W2[t];
#pragma unroll
    for (int off = 32; off > 0; off >>= 1) s += __shfl_down(s, off);
    __shared__ float w4[4];
    if ((t & 63) == 0) w4[t >> 6] = s;
    __syncthreads();
    if (t == 0) pooled[r] = w4[0] + w4[1] + w4[2] + w4[3] + b2[0];
}

__global__ void gs_bn_mlp2(const float* __restrict__ pooled, const float* __restrict__ gamma,
                           const float* __restrict__ beta, const float* __restrict__ W1,
                           const float* __restrict__ b1, const float* __restrict__ W2,
                           const float* __restrict__ b2, float* __restrict__ out) {
    __shared__ float hb[8][256];
    __shared__ float h2[8][256];
    int t = threadIdx.x;    // 256
    {
        float v[8];
        float m = 0.f;
#pragma unroll
        for (int b = 0; b < 8; ++b) { v[b] = pooled[b * 256 + t]; m += v[b]; }
        m *= 0.125f;
        float var = 0.f;
#pragma unroll
        for (int b = 0; b < 8; ++b) { float d = v[b] - m; var += d * d; }
        var *= 0.125f;
        float is = 1.0f / sqrtf(var + 1e-5f);
        float g = gamma[t], bt = beta[t];
#pragma unroll
        for (int b = 0; b < 8; ++b) hb[b][t] = fmaxf((v[b] - m) * is * g + bt, 0.f);
    }
    __syncthreads();
    {
        float acc[8] = {};
        for (int i = 0; i < 256; ++i) {
            float w = W1[i * 256 + t];
#pragma unroll
            for (int b = 0; b < 8; ++b) acc[b] = fmaf(hb[b][i], w, acc[b]);
        }
        float bb = b1[t];
#pragma unroll
        for (int b = 0; b < 8; ++b) h2[b][t] = fmaxf(acc[b] + bb, 0.f);
    }
    __syncthreads();
    if (t < 64) {
        int b = t >> 3, o = t & 7;
        float acc = 0.f;
        for (int j = 0; j < 256; ++j) acc = fmaf(h2[b][j], W2[j * 8 + o], acc);
        out[b * 8 + o] = acc + b2[o];
    }
}

extern "C" void kernel_launch(void* const* d_in, const int* in_sizes, int n_in,
                              void* d_out, int out_size, void* d_ws, size_t ws_size,
                              hipStream_t stream) {
    const float* x  = (const float*)d_in[0];
    const float* g0 = (const float*)d_in[1];
    const float* g1 = (const float*)d_in[2];
    const float* g2 = (const float*)d_in[3];
    const int* edge_src = (const int*)d_in[4];
    const int* edge_dst = (const int*)d_in[5];
    const float* Wl[4] = {(const float*)d_in[6], (const float*)d_in[9],
                          (const float*)d_in[12], (const float*)d_in[15]};
    const float* Wr[4] = {(const float*)d_in[7], (const float*)d_in[10],
                          (const float*)d_in[13], (const float*)d_in[16]};
    const float* bs[4] = {(const float*)d_in[8], (const float*)d_in[11],
                          (const float*)d_in[14], (const float*)d_in[17]};
    const float* mlp1_W1 = (const float*)d_in[18];
    const float* mlp1_b1 = (const float*)d_in[19];
    const float* mlp1_W2 = (const float*)d_in[20];
    const float* mlp1_b2 = (const float*)d_in[21];
    const float* bn_gamma = (const float*)d_in[22];
    const float* bn_beta  = (const float*)d_in[23];
    const float* mlp2_W1 = (const float*)d_in[24];
    const float* mlp2_b1 = (const float*)d_in[25];
    const float* mlp2_W2 = (const float*)d_in[26];
    const float* mlp2_b2 = (const float*)d_in[27];
    float* out = (float*)d_out;

    char* ws = (char*)d_ws;
    __hip_bfloat16* P0 = (__hip_bfloat16*)ws;                  // [ROWS][512]
    __hip_bfloat16* P1 = P0 + (size_t)ROWS * 512;              // [ROWS][512]
    __hip_bfloat16* WC0 = P1 + (size_t)ROWS * 512;             // [256][256]
    __hip_bfloat16* WC1 = WC0 + 65536;                         // [256][512]
    __hip_bfloat16* WC2 = WC1 + 131072;
    __hip_bfloat16* WC3 = WC2 + 131072;
    __hip_bfloat16* W1T = WC3 + 131072;                        // [256][8192]
    float* inv_cnt = (float*)(W1T + 2097152);
    int* ideg = (int*)(inv_cnt + 65536);
    int* prow = ideg + 65536;                                  // 65537 (+pad)
    int* cursor = prow + 65544;
    int* bsum = cursor + 65536;                                // 256
    int* pcsr = bsum + 256;                                    // PCSR_CAP
    // overlays (all inside P0/P1, mutually disjoint):
    __hip_bfloat16* H4 = P0;                                   // [2048][8192] bf16 = 32 MB
    float* pooled = (float*)P1 + 524288;                       // 8 KB at P1+2MB
    float* PART = (float*)((char*)P1 + (size_t)(4 << 20));     // 32 MB at P1+4MB

    // --- batch-1: ideg zero + 9 weight tcvt + concat (independent work) ---
    {
        B1Args a;
        const float* srcs[9] = {Wl[0], Wr[0], Wl[1], Wr[1], Wl[2], Wr[2], Wl[3], Wr[3],
                                mlp1_W1};
        __hip_bfloat16* dsts[9] = {WC0, WC0, WC1, WC1, WC2, WC2, WC3, WC3, W1T};
        int ldks[9] = {256, 256, 512, 512, 512, 512, 512, 512, 8192};
        int kofss[9] = {0, 128, 0, 256, 0, 256, 0, 256, 0};
        int kblks[9] = {4, 4, 8, 8, 8, 8, 8, 8, 256};
        for (int i = 0; i < 9; ++i) {
            a.tsrc[i] = srcs[i]; a.tdst[i] = dsts[i];
            a.ldk[i] = ldks[i]; a.kofs[i] = kofss[i]; a.kblk[i] = kblks[i];
        }
        a.x = x; a.g0 = g0; a.g1 = g1; a.g2 = g2;
        a.h = P0; a.ideg = ideg;
        gs_batch1<<<dim3(256, 8, 11), 256, 0, stream>>>(a);
    }

    // --- graph prep (hist -> reduce -> fused scan+apply -> bucket) ---
    gs_hist<<<EE / 256, 256, 0, stream>>>(edge_dst, ideg);
    gs_deg_reduce<<<256, 256, 0, stream>>>(ideg, bsum);
    gs_scan_apply<<<256, 256, 0, stream>>>(ideg, bsum, prow, cursor, inv_cnt, pcsr, P0, P1);
    gs_bucket<<<EE / 256, 256, 0, stream>>>(edge_src, edge_dst, cursor, pcsr);

    // --- 4 SAGE layers (256x256 deep-pipelined GEMM, 256 blocks = 1/CU) ---
    gs_agg_bf<128><<<NN / 4, 256, 0, stream>>>(P0 + 256, P0 + 128, prow, pcsr, inv_cnt);
    gs_gemm8_bias_relu<<<NN / 256, 512, 0, stream>>>(P0 + 128, 512, 256, WC0, 256,
                                                     bs[0], P1, 512, 256);
    gs_agg_bf<256><<<NN / 4, 256, 0, stream>>>(P1 + 256, P1, prow, pcsr, inv_cnt);
    gs_gemm8_bias_relu<<<NN / 256, 512, 0, stream>>>(P1, 512, 512, WC1, 512,
                                                     bs[1], P0, 512, 256);
    gs_agg_bf<256><<<NN / 4, 256, 0, stream>>>(P0 + 256, P0, prow, pcsr, inv_cnt);
    gs_gemm8_bias_relu<<<NN / 256, 512, 0, stream>>>(P0, 512, 512, WC2, 512,
                                                     bs[2], P1, 512, 256);
    gs_agg_bf<256><<<NN / 4, 256, 0, stream>>>(P1 + 256, P1, prow, pcsr, inv_cnt);
    gs_gemm8_bias_relu<<<NN / 256, 512, 0, stream>>>(P1, 512, 512, WC3, 512,
                                                     bs[3], H4, 256, 0);

    // --- MLP1: [2048,8192] @ [8192,256] bf16 split-K=16 -> fp32 partials ---
    gs_gemm8_splitk<<<dim3(2048 / 256, 16), 512, 0, stream>>>(H4, 8192, W1T, 8192, PART);
    gs_mlp1_pool<<<2048, 256, 0, stream>>>(PART, mlp1_b1, mlp1_W2, mlp1_b2, pooled);

    // --- BN + MLP2 -> out[8,8] ---
    gs_bn_mlp2<<<1, 256, 0, stream>>>(pooled, bn_gamma, bn_beta, mlp2_W1, mlp2_b1,
                                      mlp2_W2, mlp2_b2, out);
}